// Round 7
// baseline (232.589 us; speedup 1.0000x reference)
//
#include <hip/hip_runtime.h>
#include <cmath>

#define BATCH 8192

typedef short bf16x8 __attribute__((ext_vector_type(8)));
typedef float f32x4 __attribute__((ext_vector_type(4)));

__device__ __forceinline__ void split2(float x, unsigned short& h, unsigned short& l){
    unsigned u = __float_as_uint(x);
    unsigned hr = u + 0x7fffu + ((u >> 16) & 1u);
    unsigned short hs = (unsigned short)(hr >> 16);
    float hf = __uint_as_float(((unsigned)hs) << 16);
    float d = x - hf;
    unsigned v = __float_as_uint(d);
    unsigned short ls = (unsigned short)((v + 0x7fffu + ((v >> 16) & 1u)) >> 16);
    h = hs; l = ls;
}
__device__ __forceinline__ float fsig(float x){ return 1.f / (1.f + __expf(-x)); }
__device__ __forceinline__ float ftanh(float x){
    x = fminf(fmaxf(x, -10.f), 10.f);
    const float e = __expf(2.f*x);
    return (e - 1.f) / (e + 1.f);
}
__device__ __forceinline__ void async_copy16(void* lds, const void* g){
    __builtin_amdgcn_global_load_lds(
        (const __attribute__((address_space(1))) unsigned int*)g,
        (__attribute__((address_space(3))) unsigned int*)lds, 16, 0, 0);
}

// ---------------------------------------------------------------------------
// All preprocessing in ONE launch.
//  bx 0..15 : Wf = in_proj @ W_in (1024x512, K=256), rows<512 *conv3 -> W1 pair
//  bx 16/17 : Wt = [mu_w;ls_w] @ out_proj (128x512) -> Wt pair
//  bx 18    : b1[n] = in_proj[n,:].b_in (*conv3+conv_b for n<512)
//  bx 19    : split x_proj (48x512) -> Xp pair, rows 48..63 zeroed
//  bx 20..27: split perception (8192x512 fp32) -> Ph/Pl planes
// ---------------------------------------------------------------------------
__global__ __launch_bounds__(256) void prep_all(
    const float* __restrict__ percep,
    const float* __restrict__ in_proj, const float* __restrict__ W_in,
    const float* __restrict__ b_in,
    const float* __restrict__ mu_w, const float* __restrict__ ls_w,
    const float* __restrict__ conv_w, const float* __restrict__ conv_b,
    const float* __restrict__ out_proj, const float* __restrict__ x_proj,
    unsigned short* __restrict__ W1h, unsigned short* __restrict__ W1l,
    unsigned short* __restrict__ Wth, unsigned short* __restrict__ Wtl,
    unsigned short* __restrict__ Xph, unsigned short* __restrict__ Xpl,
    unsigned short* __restrict__ Ph, unsigned short* __restrict__ Pl,
    float* __restrict__ b1)
{
    const int bx = blockIdx.x, by = blockIdx.y;
    const int tid = threadIdx.x;
    if (bx >= 20){
        // split perception: 64 slices of 16384 float4
        const int s = (bx-20)*8 + by;
        const size_t base4 = (size_t)s*16384;
#pragma unroll 4
        for (int p=0;p<64;p++){
            const size_t i = base4 + p*256 + tid;
            float4 v = *reinterpret_cast<const float4*>(&percep[i*4]);
            unsigned short h0,h1,h2,h3,l0,l1,l2,l3;
            split2(v.x,h0,l0); split2(v.y,h1,l1); split2(v.z,h2,l2); split2(v.w,h3,l3);
            *reinterpret_cast<ushort4*>(&Ph[i*4]) = make_ushort4(h0,h1,h2,h3);
            *reinterpret_cast<ushort4*>(&Pl[i*4]) = make_ushort4(l0,l1,l2,l3);
        }
        return;
    }
    if (bx == 18){
        if (by) return;
        for (int p=0;p<4;p++){
            const int n = tid + p*256;
            float acc = 0.f;
            for (int j=0;j<256;j++) acc = fmaf(in_proj[n*256+j], b_in[j], acc);
            b1[n] = (n < 512) ? fmaf(acc, conv_w[n*4+3], conv_b[n]) : acc;
        }
        return;
    }
    if (bx == 19){
        const int n0 = by*64;
#pragma unroll
        for (int p=0;p<16;p++){
            const int idx = p*256 + tid;
            const int r = idx >> 6;
            const int c = n0 + (idx & 63);
            const float v = (r < 48) ? x_proj[(size_t)r*512 + c] : 0.f;
            unsigned short h,l; split2(v,h,l);
            Xph[(size_t)r*512+c]=h; Xpl[(size_t)r*512+c]=l;
        }
        return;
    }
    const float* A; unsigned short *Oh, *Ol; int m0; bool doscale;
    const float* B;
    if (bx < 16){ A = in_proj + (size_t)bx*64*256; B = W_in; Oh=W1h; Ol=W1l; m0=bx*64; doscale=true; }
    else { A = (bx==16 ? mu_w : ls_w); B = out_proj; Oh=Wth; Ol=Wtl; m0=(bx-16)*64; doscale=false; }
    const int n0 = by*64;

    __shared__ float As[16][68];
    __shared__ float Ws[16][68];
    const int tm = tid/16, tn = tid%16;
    float acc[4][4];
#pragma unroll
    for (int i=0;i<4;i++)
#pragma unroll
      for (int j=0;j<4;j++) acc[i][j]=0.f;

    for (int k0=0;k0<256;k0+=16){
        {
            const int kf = tid & 3, mm = tid >> 2;
            float4 v = *reinterpret_cast<const float4*>(A + (size_t)mm*256 + k0 + kf*4);
            As[kf*4+0][mm]=v.x; As[kf*4+1][mm]=v.y; As[kf*4+2][mm]=v.z; As[kf*4+3][mm]=v.w;
        }
        {
            const int nn4 = tid & 15, kk = tid >> 4;
            float4 v = *reinterpret_cast<const float4*>(B + (size_t)(k0+kk)*512 + n0 + nn4*4);
            *reinterpret_cast<float4*>(&Ws[kk][nn4*4]) = v;
        }
        __syncthreads();
#pragma unroll
        for (int k=0;k<16;k++){
            const float4 av = *reinterpret_cast<const float4*>(&As[k][tm*4]);
            const float4 bv = *reinterpret_cast<const float4*>(&Ws[k][tn*4]);
            float a[4]={av.x,av.y,av.z,av.w}, b[4]={bv.x,bv.y,bv.z,bv.w};
#pragma unroll
            for (int i=0;i<4;i++)
#pragma unroll
                for (int j=0;j<4;j++) acc[i][j] = fmaf(a[i], b[j], acc[i][j]);
        }
        __syncthreads();
    }
#pragma unroll
    for (int i=0;i<4;i++){
        const int gm = m0 + tm*4 + i;
        const float s = (doscale && gm < 512) ? conv_w[gm*4+3] : 1.f;
        const int n = n0 + tn*4;
        unsigned short h[4], l[4];
#pragma unroll
        for (int j=0;j<4;j++) split2(acc[i][j]*s, h[j], l[j]);
        *reinterpret_cast<ushort4*>(&Oh[(size_t)gm*512 + n]) = make_ushort4(h[0],h[1],h[2],h[3]);
        *reinterpret_cast<ushort4*>(&Ol[(size_t)gm*512 + n]) = make_ushort4(l[0],l[1],l[2],l[3]);
    }
}

// ---------------------------------------------------------------------------
// bf16x3 MFMA GEMM, ALL-DMA staging, double-buffered, 1 barrier per k-step,
// pass-major MFMAs.  LDS chunk order f = r*T + m == [q-plane][row][8].
// EPI 1: col<512: O0 = silu(v+bias[col]); col>=512: O1 = v+bias[col]  (fp32)
// EPI 2: col<64: O0=tanh(v+e0[col]); else O1=clip(v+e1[col-64],-5,2)
// ---------------------------------------------------------------------------
template<int TM,int TN,int WM,int WN,int EPI>
__global__ __launch_bounds__(256,2) void mgemm3(
    const unsigned short* __restrict__ Ah_g, const unsigned short* __restrict__ Al_g,
    const unsigned short* __restrict__ Bh_g, const unsigned short* __restrict__ Bl_g,
    const float* __restrict__ bias,
    const float* __restrict__ e0, const float* __restrict__ e1,
    float* __restrict__ O0, float* __restrict__ O1,
    int K)
{
    constexpr int WAVES_N = TN/WN;
    constexpr int MT = WM/16, NT = WN/16;
    constexpr int ACH = 4*TM, BCH = 4*TN;      // 16B chunks per plane per buffer
    constexpr int BUF = (2*ACH + 2*BCH)*8;     // shorts per buffer
    constexpr int IA = ACH/256, IB = BCH/256;
    __shared__ unsigned short sm[2*BUF];

    const int tid = threadIdx.x;
    const int m0 = blockIdx.x * TM;
    const int n0 = blockIdx.y * TN;
    const int lane = tid & 63, wid = tid >> 6;
    const int quad = lane >> 4, l16 = lane & 15;
    const int wm = (wid / WAVES_N) * WM;
    const int wn = (wid % WAVES_N) * WN;
    const int NK = K >> 5;

    f32x4 acc[MT][NT];
#pragma unroll
    for (int i=0;i<MT;i++)
#pragma unroll
      for (int j=0;j<NT;j++) acc[i][j] = (f32x4){0.f,0.f,0.f,0.f};

    auto dmaAll = [&](int k, int b){
        unsigned short* base = sm + b*BUF;
#pragma unroll
        for (int it=0; it<IA; ++it){
            const int f = it*256 + tid;
            const int m = f % TM, r = f / TM;
            const size_t g = (size_t)(m0+m)*K + k*32 + r*8;
            const int wb = (it*256 + wid*64)*8;
            async_copy16(base + wb,           Ah_g + g);
            async_copy16(base + ACH*8 + wb,   Al_g + g);
        }
#pragma unroll
        for (int it=0; it<IB; ++it){
            const int f = it*256 + tid;
            const int n = f % TN, r = f / TN;
            const size_t g = (size_t)(n0+n)*K + k*32 + r*8;
            const int wb = (it*256 + wid*64)*8;
            async_copy16(base + 2*ACH*8 + wb,          Bh_g + g);
            async_copy16(base + 2*ACH*8 + BCH*8 + wb,  Bl_g + g);
        }
    };

    dmaAll(0, 0);

    for (int k=0; k<NK; ++k){
        const int cur = k & 1, nxt = cur ^ 1;
        __syncthreads();                      // drains DMA -> buf[cur] ready
        if (k+1 < NK) dmaAll(k+1, nxt);

        const unsigned short* bufc = sm + cur*BUF;
        bf16x8 ah[MT], al[MT], bh[NT], bl[NT];
#pragma unroll
        for (int mt=0; mt<MT; ++mt){
            const int off = (quad*TM + wm + mt*16 + l16)*8;
            ah[mt] = *reinterpret_cast<const bf16x8*>(&bufc[off]);
            al[mt] = *reinterpret_cast<const bf16x8*>(&bufc[ACH*8 + off]);
        }
#pragma unroll
        for (int nt=0; nt<NT; ++nt){
            const int off = (quad*TN + wn + nt*16 + l16)*8;
            bh[nt] = *reinterpret_cast<const bf16x8*>(&bufc[2*ACH*8 + off]);
            bl[nt] = *reinterpret_cast<const bf16x8*>(&bufc[2*ACH*8 + BCH*8 + off]);
        }
#pragma unroll
        for (int mt=0; mt<MT; ++mt)
#pragma unroll
        for (int nt=0; nt<NT; ++nt)
            acc[mt][nt] = __builtin_amdgcn_mfma_f32_16x16x32_bf16(ah[mt], bh[nt], acc[mt][nt], 0,0,0);
#pragma unroll
        for (int mt=0; mt<MT; ++mt)
#pragma unroll
        for (int nt=0; nt<NT; ++nt)
            acc[mt][nt] = __builtin_amdgcn_mfma_f32_16x16x32_bf16(al[mt], bh[nt], acc[mt][nt], 0,0,0);
#pragma unroll
        for (int mt=0; mt<MT; ++mt)
#pragma unroll
        for (int nt=0; nt<NT; ++nt)
            acc[mt][nt] = __builtin_amdgcn_mfma_f32_16x16x32_bf16(ah[mt], bl[nt], acc[mt][nt], 0,0,0);
    }

    // C/D layout: col=lane&15, row=quad*4+reg  [m89]
#pragma unroll
    for (int mt=0; mt<MT; ++mt)
#pragma unroll
    for (int nt=0; nt<NT; ++nt)
#pragma unroll
    for (int r=0; r<4; ++r){
        const int row = m0 + wm + mt*16 + quad*4 + r;
        const int col = n0 + wn + nt*16 + l16;
        float v = acc[mt][nt][r];
        if (EPI==1){
            v += bias[col];
            if (col < 512) O0[(size_t)row*512 + col] = v * fsig(v);
            else           O1[(size_t)row*512 + (col-512)] = v;
        } else {
            if (col < 64) O0[(size_t)row*64 + col] = ftanh(v + e0[col]);
            else          O1[(size_t)row*64 + (col-64)] = fminf(fmaxf(v + e1[col-64], -5.f), 2.f);
        }
    }
}

// ---------------------------------------------------------------------------
// Fused middle: per 64-row block,
//   xdbl(64x48) = u @ x_proj.T   (bf16x3 MFMA; A=Uf split in-kernel, B=Xp DMA)
//   then SSM elementwise, Y written directly as bf16 hi/lo planes (coalesced).
// ---------------------------------------------------------------------------
__global__ __launch_bounds__(256) void g2a_ssm(
    const float* __restrict__ Uf, const float* __restrict__ Zf,
    const unsigned short* __restrict__ Xph, const unsigned short* __restrict__ Xpl,
    const float* __restrict__ dtw, const float* __restrict__ dtb,
    const float* __restrict__ dskip,
    unsigned short* __restrict__ Yh, unsigned short* __restrict__ Yl)
{
    constexpr int TM=64, TN=64, WM=32, WN=32;
    constexpr int WAVES_N = TN/WN;            // 2
    constexpr int MT = WM/16, NT = WN/16;     // 2,2
    constexpr int ACH = 4*TM, BCH = 4*TN;     // 256,256 chunks
    constexpr int BUF = (2*ACH + 2*BCH)*8;    // 8192 shorts = 16KB
    constexpr int K = 512, NK = 16;
    __shared__ unsigned short sm[2*BUF];
    __shared__ float sxd[64][49];
    __shared__ float sBC[64];

    const int tid = threadIdx.x;
    const int m0 = blockIdx.x * TM;
    const int lane = tid & 63, wid = tid >> 6;
    const int quad = lane >> 4, l16 = lane & 15;
    const int wm = (wid / WAVES_N) * WM;
    const int wn = (wid % WAVES_N) * WN;

    f32x4 acc[MT][NT];
#pragma unroll
    for (int i=0;i<MT;i++)
#pragma unroll
      for (int j=0;j<NT;j++) acc[i][j] = (f32x4){0.f,0.f,0.f,0.f};

    float4 areg[2];
    const int am = tid & 63, ar = tid >> 6;   // A chunk: f = tid = ar*64+am

    auto loadA = [&](int k){
        const float* src = Uf + (size_t)(m0+am)*K + k*32 + ar*8;
        areg[0] = *reinterpret_cast<const float4*>(src);
        areg[1] = *reinterpret_cast<const float4*>(src+4);
    };
    auto dmaB = [&](int k, int b){
        unsigned short* dst = sm + b*BUF + 2*ACH*8;
        const size_t g = (size_t)am*K + k*32 + ar*8;
        const int wb = wid*64*8;
        async_copy16(dst + wb,          Xph + g);
        async_copy16(dst + BCH*8 + wb,  Xpl + g);
    };
    auto writeA = [&](int b){
        unsigned short* dh = sm + b*BUF;
        unsigned short* dl = dh + ACH*8;
        const float* p = reinterpret_cast<const float*>(&areg[0]);
        unsigned short h[8], l[8];
#pragma unroll
        for (int j=0;j<8;j++) split2(p[j], h[j], l[j]);
        uint4 H, L;
        H.x=(unsigned)h[0]|((unsigned)h[1]<<16); H.y=(unsigned)h[2]|((unsigned)h[3]<<16);
        H.z=(unsigned)h[4]|((unsigned)h[5]<<16); H.w=(unsigned)h[6]|((unsigned)h[7]<<16);
        L.x=(unsigned)l[0]|((unsigned)l[1]<<16); L.y=(unsigned)l[2]|((unsigned)l[3]<<16);
        L.z=(unsigned)l[4]|((unsigned)l[5]<<16); L.w=(unsigned)l[6]|((unsigned)l[7]<<16);
        *reinterpret_cast<uint4*>(&dh[tid*8]) = H;
        *reinterpret_cast<uint4*>(&dl[tid*8]) = L;
    };

    loadA(0); dmaB(0,0); writeA(0);

    for (int k=0; k<NK; ++k){
        const int cur = k & 1, nxt = cur ^ 1;
        __syncthreads();
        const bool pf = (k+1 < NK);
        if (pf){ loadA(k+1); dmaB(k+1, nxt); }

        const unsigned short* bufc = sm + cur*BUF;
        bf16x8 ah[MT], al[MT], bh[NT], bl[NT];
#pragma unroll
        for (int mt=0; mt<MT; ++mt){
            const int off = (quad*TM + wm + mt*16 + l16)*8;
            ah[mt] = *reinterpret_cast<const bf16x8*>(&bufc[off]);
            al[mt] = *reinterpret_cast<const bf16x8*>(&bufc[ACH*8 + off]);
        }
#pragma unroll
        for (int nt=0; nt<NT; ++nt){
            const int off = (quad*TN + wn + nt*16 + l16)*8;
            bh[nt] = *reinterpret_cast<const bf16x8*>(&bufc[2*ACH*8 + off]);
            bl[nt] = *reinterpret_cast<const bf16x8*>(&bufc[2*ACH*8 + BCH*8 + off]);
        }
#pragma unroll
        for (int mt=0; mt<MT; ++mt)
#pragma unroll
        for (int nt=0; nt<NT; ++nt)
            acc[mt][nt] = __builtin_amdgcn_mfma_f32_16x16x32_bf16(ah[mt], bh[nt], acc[mt][nt], 0,0,0);
#pragma unroll
        for (int mt=0; mt<MT; ++mt)
#pragma unroll
        for (int nt=0; nt<NT; ++nt)
            acc[mt][nt] = __builtin_amdgcn_mfma_f32_16x16x32_bf16(al[mt], bh[nt], acc[mt][nt], 0,0,0);
#pragma unroll
        for (int mt=0; mt<MT; ++mt)
#pragma unroll
        for (int nt=0; nt<NT; ++nt)
            acc[mt][nt] = __builtin_amdgcn_mfma_f32_16x16x32_bf16(ah[mt], bl[nt], acc[mt][nt], 0,0,0);

        if (pf) writeA(nxt);
    }

    // park xdbl tile in LDS
#pragma unroll
    for (int mt=0; mt<MT; ++mt)
#pragma unroll
    for (int nt=0; nt<NT; ++nt)
#pragma unroll
    for (int r=0; r<4; ++r){
        const int row = wm + mt*16 + quad*4 + r;
        const int col = wn + nt*16 + l16;
        if (col < 48) sxd[row][col] = acc[mt][nt][r];
    }
    __syncthreads();
    if (tid < 64){
        float bc = 0.f;
#pragma unroll
        for (int n=0;n<16;n++) bc = fmaf(sxd[tid][16+n], sxd[tid][32+n], bc);
        sBC[tid] = bc;
    }
    __syncthreads();

    // elementwise: thread owns d0=tid, d1=tid+256; loop 64 rows
    const int d0 = tid, d1 = tid + 256;
    float w0[16], w1[16];
#pragma unroll
    for (int j=0;j<4;j++){
        float4 a = *reinterpret_cast<const float4*>(&dtw[d0*16 + j*4]);
        w0[j*4]=a.x; w0[j*4+1]=a.y; w0[j*4+2]=a.z; w0[j*4+3]=a.w;
        float4 b = *reinterpret_cast<const float4*>(&dtw[d1*16 + j*4]);
        w1[j*4]=b.x; w1[j*4+1]=b.y; w1[j*4+2]=b.z; w1[j*4+3]=b.w;
    }
    const float db0 = dtb[d0], db1 = dtb[d1];
    const float dk0 = dskip[d0], dk1 = dskip[d1];

#pragma unroll 2
    for (int r=0;r<64;r++){
        float xr[16];
#pragma unroll
        for (int j=0;j<16;j++) xr[j] = sxd[r][j];     // broadcast reads
        const float bc = sBC[r];
        float t0 = db0, t1 = db1;
#pragma unroll
        for (int j=0;j<16;j++){ t0 = fmaf(xr[j], w0[j], t0); t1 = fmaf(xr[j], w1[j], t1); }
        const float dl0 = (t0 > 20.f) ? t0 : __logf(1.f + __expf(t0));
        const float dl1 = (t1 > 20.f) ? t1 : __logf(1.f + __expf(t1));
        const size_t off = (size_t)(m0+r)*512;
        const float u0 = Uf[off+d0], z0 = Zf[off+d0];
        const float u1 = Uf[off+d1], z1 = Zf[off+d1];
        const float y0 = u0 * fmaf(dl0, bc, dk0) * (z0 * fsig(z0));
        const float y1 = u1 * fmaf(dl1, bc, dk1) * (z1 * fsig(z1));
        unsigned short h,l;
        split2(y0,h,l); Yh[off+d0]=h; Yl[off+d0]=l;
        split2(y1,h,l); Yh[off+d1]=h; Yl[off+d1]=l;
    }
}

extern "C" void kernel_launch(void* const* d_in, const int* in_sizes, int n_in,
                              void* d_out, int out_size, void* d_ws, size_t ws_size,
                              hipStream_t stream) {
    (void)in_sizes; (void)n_in; (void)out_size; (void)ws_size;
    const float* percep  = (const float*)d_in[0];
    const float* W_in    = (const float*)d_in[1];
    const float* b_in    = (const float*)d_in[2];
    const float* mu_w    = (const float*)d_in[3];
    const float* mu_b    = (const float*)d_in[4];
    const float* ls_w    = (const float*)d_in[5];
    const float* ls_b    = (const float*)d_in[6];
    const float* in_proj = (const float*)d_in[7];
    const float* conv_w  = (const float*)d_in[8];
    const float* conv_b  = (const float*)d_in[9];
    const float* x_proj  = (const float*)d_in[10];
    const float* dt_w    = (const float*)d_in[11];
    const float* dt_b    = (const float*)d_in[12];
    // d_in[13] A_log unused at L=1 (h0=0)
    const float* Dskip   = (const float*)d_in[14];
    const float* out_proj= (const float*)d_in[15];

    char* ws = (char*)d_ws;
    const size_t MB = 1u<<20;
    unsigned short* W1h = (unsigned short*)(ws);                      // 1 MB
    unsigned short* W1l = (unsigned short*)(ws + 1*MB);               // 1 MB
    unsigned short* Wth = (unsigned short*)(ws + 2*MB);               // 128 KB
    unsigned short* Wtl = (unsigned short*)(ws + 2*MB + 128*1024);    // 128 KB
    unsigned short* Xph = (unsigned short*)(ws + 2*MB + 256*1024);    // 64 KB
    unsigned short* Xpl = (unsigned short*)(ws + 2*MB + 320*1024);    // 64 KB
    float*          b1  = (float*)         (ws + 2*MB + 384*1024);    // 4 KB
    unsigned short* Ph  = (unsigned short*)(ws + 4*MB);               // 8 MB
    unsigned short* Pl  = (unsigned short*)(ws + 12*MB);              // 8 MB
    float*          Uf  = (float*)         (ws + 20*MB);              // 16 MB
    float*          Zf  = (float*)         (ws + 36*MB);              // 16 MB
    unsigned short* Yh  = (unsigned short*)(ws + 52*MB);              // 8 MB
    unsigned short* Yl  = (unsigned short*)(ws + 60*MB);              // 8 MB

    float* mu_o = (float*)d_out;
    float* ls_o = (float*)d_out + (size_t)BATCH*64;

    dim3 blk(256);
    // all preprocessing (weights fold/split + perception split) in one launch
    prep_all<<<dim3(28,8), blk, 0, stream>>>(
        percep, in_proj, W_in, b_in, mu_w, ls_w, conv_w, conv_b, out_proj, x_proj,
        W1h, W1l, Wth, Wtl, Xph, Xpl, Ph, Pl, b1);
    // K1: xz = p @ Wf.T + b1; u=silu -> Uf; z -> Zf   (M=8192,N=1024,K=512)
    // 128x64 tile -> 48 KB LDS -> 3 blocks/CU (was 2) for latency hiding
    mgemm3<128,64,32,64,1><<<dim3(64,16), blk, 0, stream>>>(
        Ph, Pl, W1h, W1l, b1, nullptr, nullptr, Uf, Zf, 512);
    // fused middle: xdbl GEMM + SSM -> Y planes
    g2a_ssm<<<dim3(BATCH/64), blk, 0, stream>>>(
        Uf, Zf, Xph, Xpl, dt_w, dt_b, Dskip, Yh, Yl);
    // K4: [mu|ls] = act(y @ Wt.T + b)   (M=8192,N=128,K=512)
    mgemm3<64,64,32,32,2><<<dim3(128,2), blk, 0, stream>>>(
        Yh, Yl, Wth, Wtl, nullptr, mu_b, ls_b, mu_o, ls_o, 512);
}

// Round 8
// 208.435 us; speedup vs baseline: 1.1159x; 1.1159x over previous
//
#include <hip/hip_runtime.h>
#include <cmath>

#define BATCH 8192

typedef short bf16x8 __attribute__((ext_vector_type(8)));
typedef float f32x4 __attribute__((ext_vector_type(4)));
typedef float f32x16 __attribute__((ext_vector_type(16)));

__device__ __forceinline__ void split2(float x, unsigned short& h, unsigned short& l){
    unsigned u = __float_as_uint(x);
    unsigned hr = u + 0x7fffu + ((u >> 16) & 1u);
    unsigned short hs = (unsigned short)(hr >> 16);
    float hf = __uint_as_float(((unsigned)hs) << 16);
    float d = x - hf;
    unsigned v = __float_as_uint(d);
    unsigned short ls = (unsigned short)((v + 0x7fffu + ((v >> 16) & 1u)) >> 16);
    h = hs; l = ls;
}
__device__ __forceinline__ float fsig(float x){ return 1.f / (1.f + __expf(-x)); }
__device__ __forceinline__ float ftanh(float x){
    x = fminf(fmaxf(x, -10.f), 10.f);
    const float e = __expf(2.f*x);
    return (e - 1.f) / (e + 1.f);
}
__device__ __forceinline__ void async_copy16(void* lds, const void* g){
    __builtin_amdgcn_global_load_lds(
        (const __attribute__((address_space(1))) unsigned int*)g,
        (__attribute__((address_space(3))) unsigned int*)lds, 16, 0, 0);
}

// ---------------------------------------------------------------------------
// All preprocessing in ONE launch.
//  bx 0..15 : Wf = in_proj @ W_in (1024x512, K=256), rows<512 *conv3 -> W1 pair
//  bx 16/17 : Wt = [mu_w;ls_w] @ out_proj (128x512) -> Wt pair
//  bx 18    : b1[n] = in_proj[n,:].b_in (*conv3+conv_b for n<512)
//  bx 19    : split x_proj (48x512) -> Xp pair, rows 48..63 zeroed
//  bx 20..35: split perception (8192x512 fp32) -> Ph/Pl planes (128 blocks)
// ---------------------------------------------------------------------------
__global__ __launch_bounds__(256) void prep_all(
    const float* __restrict__ percep,
    const float* __restrict__ in_proj, const float* __restrict__ W_in,
    const float* __restrict__ b_in,
    const float* __restrict__ mu_w, const float* __restrict__ ls_w,
    const float* __restrict__ conv_w, const float* __restrict__ conv_b,
    const float* __restrict__ out_proj, const float* __restrict__ x_proj,
    unsigned short* __restrict__ W1h, unsigned short* __restrict__ W1l,
    unsigned short* __restrict__ Wth, unsigned short* __restrict__ Wtl,
    unsigned short* __restrict__ Xph, unsigned short* __restrict__ Xpl,
    unsigned short* __restrict__ Ph, unsigned short* __restrict__ Pl,
    float* __restrict__ b1)
{
    const int bx = blockIdx.x, by = blockIdx.y;
    const int tid = threadIdx.x;
    if (bx >= 20){
        // split perception: 128 slices of 8192 float4
        const int s = (bx-20)*8 + by;
        const size_t base4 = (size_t)s*8192;
#pragma unroll 4
        for (int p=0;p<32;p++){
            const size_t i = base4 + p*256 + tid;
            float4 v = *reinterpret_cast<const float4*>(&percep[i*4]);
            unsigned short h0,h1,h2,h3,l0,l1,l2,l3;
            split2(v.x,h0,l0); split2(v.y,h1,l1); split2(v.z,h2,l2); split2(v.w,h3,l3);
            *reinterpret_cast<ushort4*>(&Ph[i*4]) = make_ushort4(h0,h1,h2,h3);
            *reinterpret_cast<ushort4*>(&Pl[i*4]) = make_ushort4(l0,l1,l2,l3);
        }
        return;
    }
    if (bx == 18){
        if (by) return;
        for (int p=0;p<4;p++){
            const int n = tid + p*256;
            float acc = 0.f;
            for (int j=0;j<256;j++) acc = fmaf(in_proj[n*256+j], b_in[j], acc);
            b1[n] = (n < 512) ? fmaf(acc, conv_w[n*4+3], conv_b[n]) : acc;
        }
        return;
    }
    if (bx == 19){
        const int n0 = by*64;
#pragma unroll
        for (int p=0;p<16;p++){
            const int idx = p*256 + tid;
            const int r = idx >> 6;
            const int c = n0 + (idx & 63);
            const float v = (r < 48) ? x_proj[(size_t)r*512 + c] : 0.f;
            unsigned short h,l; split2(v,h,l);
            Xph[(size_t)r*512+c]=h; Xpl[(size_t)r*512+c]=l;
        }
        return;
    }
    const float* A; unsigned short *Oh, *Ol; int m0; bool doscale;
    const float* B;
    if (bx < 16){ A = in_proj + (size_t)bx*64*256; B = W_in; Oh=W1h; Ol=W1l; m0=bx*64; doscale=true; }
    else { A = (bx==16 ? mu_w : ls_w); B = out_proj; Oh=Wth; Ol=Wtl; m0=(bx-16)*64; doscale=false; }
    const int n0 = by*64;

    __shared__ float As[16][68];
    __shared__ float Ws[16][68];
    const int tm = tid/16, tn = tid%16;
    float acc[4][4];
#pragma unroll
    for (int i=0;i<4;i++)
#pragma unroll
      for (int j=0;j<4;j++) acc[i][j]=0.f;

    for (int k0=0;k0<256;k0+=16){
        {
            const int kf = tid & 3, mm = tid >> 2;
            float4 v = *reinterpret_cast<const float4*>(A + (size_t)mm*256 + k0 + kf*4);
            As[kf*4+0][mm]=v.x; As[kf*4+1][mm]=v.y; As[kf*4+2][mm]=v.z; As[kf*4+3][mm]=v.w;
        }
        {
            const int nn4 = tid & 15, kk = tid >> 4;
            float4 v = *reinterpret_cast<const float4*>(B + (size_t)(k0+kk)*512 + n0 + nn4*4);
            *reinterpret_cast<float4*>(&Ws[kk][nn4*4]) = v;
        }
        __syncthreads();
#pragma unroll
        for (int k=0;k<16;k++){
            const float4 av = *reinterpret_cast<const float4*>(&As[k][tm*4]);
            const float4 bv = *reinterpret_cast<const float4*>(&Ws[k][tn*4]);
            float a[4]={av.x,av.y,av.z,av.w}, b[4]={bv.x,bv.y,bv.z,bv.w};
#pragma unroll
            for (int i=0;i<4;i++)
#pragma unroll
                for (int j=0;j<4;j++) acc[i][j] = fmaf(a[i], b[j], acc[i][j]);
        }
        __syncthreads();
    }
#pragma unroll
    for (int i=0;i<4;i++){
        const int gm = m0 + tm*4 + i;
        const float s = (doscale && gm < 512) ? conv_w[gm*4+3] : 1.f;
        const int n = n0 + tn*4;
        unsigned short h[4], l[4];
#pragma unroll
        for (int j=0;j<4;j++) split2(acc[i][j]*s, h[j], l[j]);
        *reinterpret_cast<ushort4*>(&Oh[(size_t)gm*512 + n]) = make_ushort4(h[0],h[1],h[2],h[3]);
        *reinterpret_cast<ushort4*>(&Ol[(size_t)gm*512 + n]) = make_ushort4(l[0],l[1],l[2],l[3]);
    }
}

// ---------------------------------------------------------------------------
// bf16x3 MFMA GEMM on 32x32x16 MFMA, ALL-DMA staging, double-buffered,
// 1 barrier per k-step, pass-major. LDS layout [r][row][8], frag r = j*2+half.
// C/D: col=lane&31, row=(reg&3)+8*(reg>>2)+4*(lane>>5)  [m74/m101]
// EPI 1: col<512: O0 = silu(v+bias[col]); col>=512: O1 = v+bias[col]  (fp32)
// ---------------------------------------------------------------------------
template<int TM,int TN,int WM,int WN,int EPI>
__global__ __launch_bounds__(256,2) void mgemm4(
    const unsigned short* __restrict__ Ah_g, const unsigned short* __restrict__ Al_g,
    const unsigned short* __restrict__ Bh_g, const unsigned short* __restrict__ Bl_g,
    const float* __restrict__ bias,
    float* __restrict__ O0, float* __restrict__ O1,
    int K)
{
    constexpr int WAVES_N = TN/WN;
    constexpr int MT = WM/32, NT = WN/32;
    constexpr int ACH = 4*TM, BCH = 4*TN;
    constexpr int BUF = (2*ACH + 2*BCH)*8;
    constexpr int IA = ACH/256, IB = BCH/256;
    __shared__ unsigned short sm[2*BUF];

    const int tid = threadIdx.x;
    const int m0 = blockIdx.x * TM;
    const int n0 = blockIdx.y * TN;
    const int lane = tid & 63, wid = tid >> 6;
    const int half = lane >> 5, l32 = lane & 31;
    const int wm = (wid / WAVES_N) * WM;
    const int wn = (wid % WAVES_N) * WN;
    const int NK = K >> 5;

    f32x16 acc[MT][NT];
#pragma unroll
    for (int i=0;i<MT;i++)
#pragma unroll
      for (int j=0;j<NT;j++)
#pragma unroll
        for (int r=0;r<16;r++) acc[i][j][r] = 0.f;

    auto dmaAll = [&](int k, int b){
        unsigned short* base = sm + b*BUF;
#pragma unroll
        for (int it=0; it<IA; ++it){
            const int f = it*256 + tid;
            const int m = f % TM, r = f / TM;
            const size_t g = (size_t)(m0+m)*K + k*32 + r*8;
            const int wb = (it*256 + wid*64)*8;
            async_copy16(base + wb,           Ah_g + g);
            async_copy16(base + ACH*8 + wb,   Al_g + g);
        }
#pragma unroll
        for (int it=0; it<IB; ++it){
            const int f = it*256 + tid;
            const int n = f % TN, r = f / TN;
            const size_t g = (size_t)(n0+n)*K + k*32 + r*8;
            const int wb = (it*256 + wid*64)*8;
            async_copy16(base + 2*ACH*8 + wb,          Bh_g + g);
            async_copy16(base + 2*ACH*8 + BCH*8 + wb,  Bl_g + g);
        }
    };

    dmaAll(0, 0);

    for (int k=0; k<NK; ++k){
        const int cur = k & 1, nxt = cur ^ 1;
        __syncthreads();
        if (k+1 < NK) dmaAll(k+1, nxt);

        const unsigned short* bufc = sm + cur*BUF;
        bf16x8 ah[2][MT], al[2][MT], bh[2][NT], bl[2][NT];
#pragma unroll
        for (int j=0;j<2;j++){
            const int r = j*2 + half;
#pragma unroll
            for (int mt=0; mt<MT; ++mt){
                const int off = (r*TM + wm + mt*32 + l32)*8;
                ah[j][mt] = *reinterpret_cast<const bf16x8*>(&bufc[off]);
                al[j][mt] = *reinterpret_cast<const bf16x8*>(&bufc[ACH*8 + off]);
            }
#pragma unroll
            for (int nt=0; nt<NT; ++nt){
                const int off = (r*TN + wn + nt*32 + l32)*8;
                bh[j][nt] = *reinterpret_cast<const bf16x8*>(&bufc[2*ACH*8 + off]);
                bl[j][nt] = *reinterpret_cast<const bf16x8*>(&bufc[2*ACH*8 + BCH*8 + off]);
            }
        }
#pragma unroll
        for (int j=0;j<2;j++){
#pragma unroll
            for (int mt=0; mt<MT; ++mt)
#pragma unroll
            for (int nt=0; nt<NT; ++nt)
                acc[mt][nt] = __builtin_amdgcn_mfma_f32_32x32x16_bf16(ah[j][mt], bh[j][nt], acc[mt][nt], 0,0,0);
#pragma unroll
            for (int mt=0; mt<MT; ++mt)
#pragma unroll
            for (int nt=0; nt<NT; ++nt)
                acc[mt][nt] = __builtin_amdgcn_mfma_f32_32x32x16_bf16(al[j][mt], bh[j][nt], acc[mt][nt], 0,0,0);
#pragma unroll
            for (int mt=0; mt<MT; ++mt)
#pragma unroll
            for (int nt=0; nt<NT; ++nt)
                acc[mt][nt] = __builtin_amdgcn_mfma_f32_32x32x16_bf16(ah[j][mt], bl[j][nt], acc[mt][nt], 0,0,0);
        }
    }

#pragma unroll
    for (int mt=0; mt<MT; ++mt)
#pragma unroll
    for (int nt=0; nt<NT; ++nt)
#pragma unroll
    for (int r=0; r<16; ++r){
        const int row = m0 + wm + mt*32 + (r&3) + 8*(r>>2) + 4*half;
        const int col = n0 + wn + nt*32 + l32;
        float v = acc[mt][nt][r];
        if (EPI==1){
            v += bias[col];
            if (col < 512) O0[(size_t)row*512 + col] = v * fsig(v);
            else           O1[(size_t)row*512 + (col-512)] = v;
        } else {
            O0[(size_t)row*TN + col] = v;
        }
    }
}

// ---------------------------------------------------------------------------
// bf16x3 MFMA GEMM (16x16x32), ALL-DMA, dbuf, pass-major — kept for K4.
// EPI 2: col<64: O0=tanh(v+e0[col]); else O1=clip(v+e1[col-64],-5,2)
// ---------------------------------------------------------------------------
template<int TM,int TN,int WM,int WN,int EPI>
__global__ __launch_bounds__(256,2) void mgemm3(
    const unsigned short* __restrict__ Ah_g, const unsigned short* __restrict__ Al_g,
    const unsigned short* __restrict__ Bh_g, const unsigned short* __restrict__ Bl_g,
    const float* __restrict__ e0, const float* __restrict__ e1,
    float* __restrict__ O0, float* __restrict__ O1,
    int K)
{
    constexpr int WAVES_N = TN/WN;
    constexpr int MT = WM/16, NT = WN/16;
    constexpr int ACH = 4*TM, BCH = 4*TN;
    constexpr int BUF = (2*ACH + 2*BCH)*8;
    constexpr int IA = ACH/256, IB = BCH/256;
    __shared__ unsigned short sm[2*BUF];

    const int tid = threadIdx.x;
    const int m0 = blockIdx.x * TM;
    const int n0 = blockIdx.y * TN;
    const int lane = tid & 63, wid = tid >> 6;
    const int quad = lane >> 4, l16 = lane & 15;
    const int wm = (wid / WAVES_N) * WM;
    const int wn = (wid % WAVES_N) * WN;
    const int NK = K >> 5;

    f32x4 acc[MT][NT];
#pragma unroll
    for (int i=0;i<MT;i++)
#pragma unroll
      for (int j=0;j<NT;j++) acc[i][j] = (f32x4){0.f,0.f,0.f,0.f};

    auto dmaAll = [&](int k, int b){
        unsigned short* base = sm + b*BUF;
#pragma unroll
        for (int it=0; it<IA; ++it){
            const int f = it*256 + tid;
            const int m = f % TM, r = f / TM;
            const size_t g = (size_t)(m0+m)*K + k*32 + r*8;
            const int wb = (it*256 + wid*64)*8;
            async_copy16(base + wb,           Ah_g + g);
            async_copy16(base + ACH*8 + wb,   Al_g + g);
        }
#pragma unroll
        for (int it=0; it<IB; ++it){
            const int f = it*256 + tid;
            const int n = f % TN, r = f / TN;
            const size_t g = (size_t)(n0+n)*K + k*32 + r*8;
            const int wb = (it*256 + wid*64)*8;
            async_copy16(base + 2*ACH*8 + wb,          Bh_g + g);
            async_copy16(base + 2*ACH*8 + BCH*8 + wb,  Bl_g + g);
        }
    };

    dmaAll(0, 0);

    for (int k=0; k<NK; ++k){
        const int cur = k & 1, nxt = cur ^ 1;
        __syncthreads();
        if (k+1 < NK) dmaAll(k+1, nxt);

        const unsigned short* bufc = sm + cur*BUF;
        bf16x8 ah[MT], al[MT], bh[NT], bl[NT];
#pragma unroll
        for (int mt=0; mt<MT; ++mt){
            const int off = (quad*TM + wm + mt*16 + l16)*8;
            ah[mt] = *reinterpret_cast<const bf16x8*>(&bufc[off]);
            al[mt] = *reinterpret_cast<const bf16x8*>(&bufc[ACH*8 + off]);
        }
#pragma unroll
        for (int nt=0; nt<NT; ++nt){
            const int off = (quad*TN + wn + nt*16 + l16)*8;
            bh[nt] = *reinterpret_cast<const bf16x8*>(&bufc[2*ACH*8 + off]);
            bl[nt] = *reinterpret_cast<const bf16x8*>(&bufc[2*ACH*8 + BCH*8 + off]);
        }
#pragma unroll
        for (int mt=0; mt<MT; ++mt)
#pragma unroll
        for (int nt=0; nt<NT; ++nt)
            acc[mt][nt] = __builtin_amdgcn_mfma_f32_16x16x32_bf16(ah[mt], bh[nt], acc[mt][nt], 0,0,0);
#pragma unroll
        for (int mt=0; mt<MT; ++mt)
#pragma unroll
        for (int nt=0; nt<NT; ++nt)
            acc[mt][nt] = __builtin_amdgcn_mfma_f32_16x16x32_bf16(al[mt], bh[nt], acc[mt][nt], 0,0,0);
#pragma unroll
        for (int mt=0; mt<MT; ++mt)
#pragma unroll
        for (int nt=0; nt<NT; ++nt)
            acc[mt][nt] = __builtin_amdgcn_mfma_f32_16x16x32_bf16(ah[mt], bl[nt], acc[mt][nt], 0,0,0);
    }

#pragma unroll
    for (int mt=0; mt<MT; ++mt)
#pragma unroll
    for (int nt=0; nt<NT; ++nt)
#pragma unroll
    for (int r=0; r<4; ++r){
        const int row = m0 + wm + mt*16 + quad*4 + r;
        const int col = n0 + wn + nt*16 + l16;
        float v = acc[mt][nt][r];
        if (col < 64) O0[(size_t)row*64 + col] = ftanh(v + e0[col]);
        else          O1[(size_t)row*64 + (col-64)] = fminf(fmaxf(v + e1[col-64], -5.f), 2.f);
    }
}

// ---------------------------------------------------------------------------
// Fused middle, 32 rows/block (grid 256 = all CUs):
//   xdbl(32x48) = u @ x_proj.T  (bf16x3; A=Uf split in-kernel, B=Xp DMA)
//   then SSM elementwise, Y -> bf16 hi/lo planes coalesced.
// Waves 2x2: WM=16, WN=32 -> MT=1, NT=2.
// ---------------------------------------------------------------------------
__global__ __launch_bounds__(256) void g2a_ssm(
    const float* __restrict__ Uf, const float* __restrict__ Zf,
    const unsigned short* __restrict__ Xph, const unsigned short* __restrict__ Xpl,
    const float* __restrict__ dtw, const float* __restrict__ dtb,
    const float* __restrict__ dskip,
    unsigned short* __restrict__ Yh, unsigned short* __restrict__ Yl)
{
    constexpr int TM=32, TN=64;
    constexpr int NT = 2;
    constexpr int ACH = 4*TM, BCH = 4*TN;       // 128, 256 chunks
    constexpr int BUF = (2*ACH + 2*BCH)*8;      // 6144 shorts = 12 KB
    constexpr int K = 512, NK = 16;
    __shared__ unsigned short sm[2*BUF];
    __shared__ float sxd[32][49];
    __shared__ float sBC[32];

    const int tid = threadIdx.x;
    const int m0 = blockIdx.x * TM;
    const int lane = tid & 63, wid = tid >> 6;
    const int quad = lane >> 4, l16 = lane & 15;
    const int wm = (wid >> 1) * 16;
    const int wn = (wid & 1) * 32;

    f32x4 acc[NT];
#pragma unroll
    for (int j=0;j<NT;j++) acc[j] = (f32x4){0.f,0.f,0.f,0.f};

    float4 areg[2];
    const int am = tid & 31, ar = (tid >> 5) & 3;  // chunk f = ar*32+am for tid<128

    auto loadA = [&](int k){
        if (tid < 128){
            const float* src = Uf + (size_t)(m0+am)*K + k*32 + ar*8;
            areg[0] = *reinterpret_cast<const float4*>(src);
            areg[1] = *reinterpret_cast<const float4*>(src+4);
        }
    };
    auto dmaB = [&](int k, int b){
        unsigned short* dst = sm + b*BUF + 2*ACH*8;
        const int n = tid & 63, r = tid >> 6;
        const size_t g = (size_t)n*K + k*32 + r*8;
        const int wb = wid*64*8;
        async_copy16(dst + wb,          Xph + g);
        async_copy16(dst + BCH*8 + wb,  Xpl + g);
    };
    auto writeA = [&](int b){
        if (tid < 128){
            unsigned short* dh = sm + b*BUF;
            unsigned short* dl = dh + ACH*8;
            const float* p = reinterpret_cast<const float*>(&areg[0]);
            unsigned short h[8], l[8];
#pragma unroll
            for (int j=0;j<8;j++) split2(p[j], h[j], l[j]);
            uint4 H, L;
            H.x=(unsigned)h[0]|((unsigned)h[1]<<16); H.y=(unsigned)h[2]|((unsigned)h[3]<<16);
            H.z=(unsigned)h[4]|((unsigned)h[5]<<16); H.w=(unsigned)h[6]|((unsigned)h[7]<<16);
            L.x=(unsigned)l[0]|((unsigned)l[1]<<16); L.y=(unsigned)l[2]|((unsigned)l[3]<<16);
            L.z=(unsigned)l[4]|((unsigned)l[5]<<16); L.w=(unsigned)l[6]|((unsigned)l[7]<<16);
            const int f = (tid >> 5)*32 + am;       // == ar*32+am
            *reinterpret_cast<uint4*>(&dh[f*8]) = H;
            *reinterpret_cast<uint4*>(&dl[f*8]) = L;
        }
    };

    loadA(0); dmaB(0,0); writeA(0);

    for (int k=0; k<NK; ++k){
        const int cur = k & 1, nxt = cur ^ 1;
        __syncthreads();
        const bool pf = (k+1 < NK);
        if (pf){ loadA(k+1); dmaB(k+1, nxt); }

        const unsigned short* bufc = sm + cur*BUF;
        bf16x8 ah, al, bh[NT], bl[NT];
        {
            const int off = (quad*TM + wm + l16)*8;
            ah = *reinterpret_cast<const bf16x8*>(&bufc[off]);
            al = *reinterpret_cast<const bf16x8*>(&bufc[ACH*8 + off]);
        }
#pragma unroll
        for (int nt=0; nt<NT; ++nt){
            const int off = (quad*TN + wn + nt*16 + l16)*8;
            bh[nt] = *reinterpret_cast<const bf16x8*>(&bufc[2*ACH*8 + off]);
            bl[nt] = *reinterpret_cast<const bf16x8*>(&bufc[2*ACH*8 + BCH*8 + off]);
        }
#pragma unroll
        for (int nt=0; nt<NT; ++nt)
            acc[nt] = __builtin_amdgcn_mfma_f32_16x16x32_bf16(ah, bh[nt], acc[nt], 0,0,0);
#pragma unroll
        for (int nt=0; nt<NT; ++nt)
            acc[nt] = __builtin_amdgcn_mfma_f32_16x16x32_bf16(al, bh[nt], acc[nt], 0,0,0);
#pragma unroll
        for (int nt=0; nt<NT; ++nt)
            acc[nt] = __builtin_amdgcn_mfma_f32_16x16x32_bf16(ah, bl[nt], acc[nt], 0,0,0);

        if (pf) writeA(nxt);
    }

    // park xdbl tile
#pragma unroll
    for (int nt=0; nt<NT; ++nt)
#pragma unroll
    for (int r=0; r<4; ++r){
        const int row = wm + quad*4 + r;
        const int col = wn + nt*16 + l16;
        if (col < 48) sxd[row][col] = acc[nt][r];
    }
    __syncthreads();
    if (tid < 32){
        float bc = 0.f;
#pragma unroll
        for (int n=0;n<16;n++) bc = fmaf(sxd[tid][16+n], sxd[tid][32+n], bc);
        sBC[tid] = bc;
    }
    __syncthreads();

    // elementwise: thread owns d0=tid, d1=tid+256; loop 32 rows
    const int d0 = tid, d1 = tid + 256;
    float w0[16], w1[16];
#pragma unroll
    for (int j=0;j<4;j++){
        float4 a = *reinterpret_cast<const float4*>(&dtw[d0*16 + j*4]);
        w0[j*4]=a.x; w0[j*4+1]=a.y; w0[j*4+2]=a.z; w0[j*4+3]=a.w;
        float4 b = *reinterpret_cast<const float4*>(&dtw[d1*16 + j*4]);
        w1[j*4]=b.x; w1[j*4+1]=b.y; w1[j*4+2]=b.z; w1[j*4+3]=b.w;
    }
    const float db0 = dtb[d0], db1 = dtb[d1];
    const float dk0 = dskip[d0], dk1 = dskip[d1];

#pragma unroll 2
    for (int r=0;r<32;r++){
        float xr[16];
#pragma unroll
        for (int j=0;j<16;j++) xr[j] = sxd[r][j];
        const float bc = sBC[r];
        float t0 = db0, t1 = db1;
#pragma unroll
        for (int j=0;j<16;j++){ t0 = fmaf(xr[j], w0[j], t0); t1 = fmaf(xr[j], w1[j], t1); }
        const float dl0 = (t0 > 20.f) ? t0 : __logf(1.f + __expf(t0));
        const float dl1 = (t1 > 20.f) ? t1 : __logf(1.f + __expf(t1));
        const size_t off = (size_t)(m0+r)*512;
        const float u0 = Uf[off+d0], z0 = Zf[off+d0];
        const float u1 = Uf[off+d1], z1 = Zf[off+d1];
        const float y0 = u0 * fmaf(dl0, bc, dk0) * (z0 * fsig(z0));
        const float y1 = u1 * fmaf(dl1, bc, dk1) * (z1 * fsig(z1));
        unsigned short h,l;
        split2(y0,h,l); Yh[off+d0]=h; Yl[off+d0]=l;
        split2(y1,h,l); Yh[off+d1]=h; Yl[off+d1]=l;
    }
}

extern "C" void kernel_launch(void* const* d_in, const int* in_sizes, int n_in,
                              void* d_out, int out_size, void* d_ws, size_t ws_size,
                              hipStream_t stream) {
    (void)in_sizes; (void)n_in; (void)out_size; (void)ws_size;
    const float* percep  = (const float*)d_in[0];
    const float* W_in    = (const float*)d_in[1];
    const float* b_in    = (const float*)d_in[2];
    const float* mu_w    = (const float*)d_in[3];
    const float* mu_b    = (const float*)d_in[4];
    const float* ls_w    = (const float*)d_in[5];
    const float* ls_b    = (const float*)d_in[6];
    const float* in_proj = (const float*)d_in[7];
    const float* conv_w  = (const float*)d_in[8];
    const float* conv_b  = (const float*)d_in[9];
    const float* x_proj  = (const float*)d_in[10];
    const float* dt_w    = (const float*)d_in[11];
    const float* dt_b    = (const float*)d_in[12];
    // d_in[13] A_log unused at L=1 (h0=0)
    const float* Dskip   = (const float*)d_in[14];
    const float* out_proj= (const float*)d_in[15];

    char* ws = (char*)d_ws;
    const size_t MB = 1u<<20;
    unsigned short* W1h = (unsigned short*)(ws);                      // 1 MB
    unsigned short* W1l = (unsigned short*)(ws + 1*MB);               // 1 MB
    unsigned short* Wth = (unsigned short*)(ws + 2*MB);               // 128 KB
    unsigned short* Wtl = (unsigned short*)(ws + 2*MB + 128*1024);    // 128 KB
    unsigned short* Xph = (unsigned short*)(ws + 2*MB + 256*1024);    // 64 KB
    unsigned short* Xpl = (unsigned short*)(ws + 2*MB + 320*1024);    // 64 KB
    float*          b1  = (float*)         (ws + 2*MB + 384*1024);    // 4 KB
    unsigned short* Ph  = (unsigned short*)(ws + 4*MB);               // 8 MB
    unsigned short* Pl  = (unsigned short*)(ws + 12*MB);              // 8 MB
    float*          Uf  = (float*)         (ws + 20*MB);              // 16 MB
    float*          Zf  = (float*)         (ws + 36*MB);              // 16 MB
    unsigned short* Yh  = (unsigned short*)(ws + 52*MB);              // 8 MB
    unsigned short* Yl  = (unsigned short*)(ws + 60*MB);              // 8 MB

    float* mu_o = (float*)d_out;
    float* ls_o = (float*)d_out + (size_t)BATCH*64;

    dim3 blk(256);
    prep_all<<<dim3(36,8), blk, 0, stream>>>(
        percep, in_proj, W_in, b_in, mu_w, ls_w, conv_w, conv_b, out_proj, x_proj,
        W1h, W1l, Wth, Wtl, Xph, Xpl, Ph, Pl, b1);
    // K1: 128x128 tile (R6 best), 32x32x16 MFMA core
    mgemm4<128,128,64,64,1><<<dim3(64,8), blk, 0, stream>>>(
        Ph, Pl, W1h, W1l, b1, Uf, Zf, 512);
    // fused middle: 256 blocks (all CUs)
    g2a_ssm<<<dim3(BATCH/32), blk, 0, stream>>>(
        Uf, Zf, Xph, Xpl, dt_w, dt_b, Dskip, Yh, Yl);
    // K4: [mu|ls] = act(y @ Wt.T + b)
    mgemm3<64,64,32,32,2><<<dim3(128,2), blk, 0, stream>>>(
        Yh, Yl, Wth, Wtl, mu_b, ls_b, mu_o, ls_o, 512);
}